// Round 2
// baseline (95.036 us; speedup 1.0000x reference)
//
#include <hip/hip_runtime.h>

// probs [N,T,K] f32, targets [N,L] int64->int32 view? (harness: integer -> const int*)
constexpr int N_ = 32;
constexpr int T_ = 256;
constexpr int K_ = 8000;
constexpr int L_ = 64;
constexpr int NBLK = N_ * L_;   // 2048 blocks, one per (n,l) column

// Fused: per-block column sum + -log, then last-arriving block reduces all
// partials and writes the scalar output. Counter is memset to 0 each call.
__global__ __launch_bounds__(256) void ACE_fused(
    const float* __restrict__ probs,
    const int* __restrict__ targets,
    float* __restrict__ partial,          // [NBLK]
    unsigned int* __restrict__ counter,   // memset to 0 before launch
    float* __restrict__ out) {
    const int bid = blockIdx.x;           // == n*L + l
    const int n = bid >> 6;               // L == 64
    const int t = threadIdx.x;            // 0..255 == time step

    const int k = targets[bid];           // targets[n][l] flat == targets[bid]
    const size_t idx = ((size_t)(n * T_ + t)) * (size_t)K_ + (size_t)k;
    float v = probs[idx];

    // 64-lane wave reduce
    #pragma unroll
    for (int off = 32; off > 0; off >>= 1)
        v += __shfl_down(v, off, 64);

    __shared__ float wsum[4];
    __shared__ bool is_last;
    if ((t & 63) == 0) wsum[t >> 6] = v;
    __syncthreads();

    if (t == 0) {
        const float s = wsum[0] + wsum[1] + wsum[2] + wsum[3];
        const float meanp = s * (1.0f / (float)T_) + 1e-10f;
        // release store so the last block sees it after its acquire RMW
        __hip_atomic_store(&partial[bid], -logf(meanp),
                           __ATOMIC_RELEASE, __HIP_MEMORY_SCOPE_AGENT);
        const unsigned int ticket = __hip_atomic_fetch_add(
            counter, 1u, __ATOMIC_ACQ_REL, __HIP_MEMORY_SCOPE_AGENT);
        is_last = (ticket == (unsigned int)(NBLK - 1));
    }
    __syncthreads();

    if (is_last) {
        // reduce 2048 partials (deterministic order independent of which
        // physical block executes this)
        float s = 0.0f;
        #pragma unroll
        for (int j = 0; j < NBLK / 256; ++j) {
            const int i = t + j * 256;
            s += __hip_atomic_load(&partial[i], __ATOMIC_RELAXED,
                                   __HIP_MEMORY_SCOPE_AGENT);
        }
        #pragma unroll
        for (int off = 32; off > 0; off >>= 1)
            s += __shfl_down(s, off, 64);
        if ((t & 63) == 0) wsum[t >> 6] = s;
        __syncthreads();
        if (t == 0) {
            const float total = wsum[0] + wsum[1] + wsum[2] + wsum[3];
            out[0] = total * (1.0f / ((float)N_ * (float)T_));
        }
    }
}

extern "C" void kernel_launch(void* const* d_in, const int* in_sizes, int n_in,
                              void* d_out, int out_size, void* d_ws, size_t ws_size,
                              hipStream_t stream) {
    const float* probs = (const float*)d_in[0];
    const int* targets = (const int*)d_in[1];
    float* out = (float*)d_out;

    unsigned int* counter = (unsigned int*)d_ws;                 // 4 bytes
    float* partial = (float*)((char*)d_ws + 256);                // NBLK floats

    hipMemsetAsync(d_ws, 0, 4, stream);                          // zero ticket
    ACE_fused<<<NBLK, 256, 0, stream>>>(probs, targets, partial, counter, out);
}